// Round 7
// baseline (149.055 us; speedup 1.0000x reference)
//
#include <hip/hip_runtime.h>

// SSIM loss, 7x7 uniform window, VALID, over (64,1,512,512) fp32.
// R7: barrier-free main loop. Each wave owns a private 64-col strip and a
// private LDS row buffer (wave-synchronous: DS ops of a wave execute in
// order, so write->read needs no __syncthreads). 4 independent waves/block,
// SH=64 rows/block. Keep: row prefetch, fast rcp, no launch_bounds pin.

constexpr int B  = 64;
constexpr int H  = 512, W = 512;
constexpr int OH = H - 6, OW = W - 6;     // 506
constexpr int CW = 64;                    // output cols per wave
constexpr int SH = 64;                    // output rows per block

constexpr float INV_NP    = 1.0f / 49.0f;
constexpr float COV_NORM  = 49.0f / 48.0f;

__global__ __launch_bounds__(256)
void ssim_main(const float* __restrict__ X, const float* __restrict__ Y,
               const float* __restrict__ DR, float* __restrict__ partials)
{
    const int tid  = threadIdx.x;
    const int wid  = tid >> 6;
    const int lane = tid & 63;
    const int c0   = blockIdx.x * CW;   // 0..448
    const int r0   = blockIdx.y * SH;   // 0..448
    const int b    = blockIdx.z;

    const int out_rows = min(SH, OH - r0);
    const int rows_in  = out_rows + 6;       // <= 70

    const float d  = DR[b];
    const float C1 = (0.01f * d) * (0.01f * d);
    const float C2 = (0.03f * d) * (0.03f * d);

    const size_t base = (size_t)b * H * W + (size_t)r0 * W;
    const float* xp  = X + base + c0 + lane;
    const float* yp  = Y + base + c0 + lane;
    const float* xph = X + base + c0 + CW + lane;   // halo, lanes 0..5
    const float* yph = Y + base + c0 + CW + lane;

    const bool halo_ok  = (lane < 6) && (c0 + CW + lane < W);
    const bool colvalid = (c0 + lane) < OW;

    // wave-private double-buffered row: {x,y} pairs, 70 used per slot
    __shared__ float2 rb[4][2][CW + 8];

    // vertical circular buffers (statically indexed via 7x unroll)
    float bx[7], by[7], bxx[7], byy[7], bxy[7];
    float vsx = 0.f, vsy = 0.f, vsxx = 0.f, vsyy = 0.f, vsxy = 0.f;
#pragma unroll
    for (int i = 0; i < 7; ++i) { bx[i]=by[i]=bxx[i]=byy[i]=bxy[i]=0.f; }

    float acc = 0.f;

    // prefetch registers for the next input row
    float2 pre, preh;
    pre.x  = xp[0];
    pre.y  = yp[0];
    preh.x = halo_ok ? xph[0] : 0.f;
    preh.y = halo_ok ? yph[0] : 0.f;
    xp += W; yp += W; xph += W; yph += W;

    for (int rr = 0; rr < 70; rr += 7) {
#pragma unroll
        for (int p = 0; p < 7; ++p) {
            const int r = rr + p;                  // r % 7 == p
            if (r < rows_in) {                     // block-uniform condition
                float2* buf = rb[wid][r & 1];
                buf[lane] = pre;
                if (lane < 6) buf[CW + lane] = preh;
                // no barrier: wave-private region, DS ops in order per wave

                // issue next row's global loads; latency hides under compute
                if (r + 1 < rows_in) {
                    pre.x = xp[0];
                    pre.y = yp[0];
                    if (lane < 6) {
                        preh.x = halo_ok ? xph[0] : 0.f;
                        preh.y = halo_ok ? yph[0] : 0.f;
                    }
                    xp += W; yp += W; xph += W; yph += W;
                }

                // horizontal 7-tap sums of the 5 channels
                float hx = 0.f, hy = 0.f, hxx = 0.f, hyy = 0.f, hxy = 0.f;
#pragma unroll
                for (int i = 0; i < 7; ++i) {
                    const float2 v = buf[lane + i];
                    hx += v.x; hy += v.y;
                    hxx = fmaf(v.x, v.x, hxx);
                    hyy = fmaf(v.y, v.y, hyy);
                    hxy = fmaf(v.x, v.y, hxy);
                }

                // vertical running 7-row window (slot p holds row r-7's value)
                vsx  += hx  - bx[p];  bx[p]  = hx;
                vsy  += hy  - by[p];  by[p]  = hy;
                vsxx += hxx - bxx[p]; bxx[p] = hxx;
                vsyy += hyy - byy[p]; byy[p] = hyy;
                vsxy += hxy - bxy[p]; bxy[p] = hxy;

                if (r >= 6 && colvalid) {
                    const float ux  = vsx  * INV_NP;
                    const float uy  = vsy  * INV_NP;
                    const float uxx = vsxx * INV_NP;
                    const float uyy = vsyy * INV_NP;
                    const float uxy = vsxy * INV_NP;
                    const float vx  = COV_NORM * (uxx - ux * ux);
                    const float vy  = COV_NORM * (uyy - uy * uy);
                    const float vxy = COV_NORM * (uxy - ux * uy);
                    const float A1 = 2.f * ux * uy + C1;
                    const float A2 = 2.f * vxy + C2;
                    const float B1 = ux * ux + uy * uy + C1;
                    const float B2 = vx + vy + C2;
                    const float den = B1 * B2;
                    float rcp = __builtin_amdgcn_rcpf(den);
                    rcp = rcp * (2.f - den * rcp);      // 1 Newton step
                    acc = fmaf(A1 * A2, rcp, acc);
                }
            }
        }
    }

    // block reduction: wave shfl, then cross-wave via LDS (single barrier)
    float s = acc;
#pragma unroll
    for (int off = 32; off; off >>= 1) s += __shfl_down(s, off, 64);
    __shared__ float wsum[4];
    if (lane == 0) wsum[wid] = s;
    __syncthreads();
    if (tid == 0) {
        const int bid = (blockIdx.z * gridDim.y + blockIdx.y) * gridDim.x + blockIdx.x;
        partials[bid] = wsum[0] + wsum[1] + wsum[2] + wsum[3];
    }
}

__global__ __launch_bounds__(256)
void ssim_final(const float* __restrict__ partials, int n,
                float* __restrict__ out, float inv_count)
{
    const int tid = threadIdx.x;
    float s = 0.f;
    for (int i = tid; i < n; i += 256) s += partials[i];
#pragma unroll
    for (int off = 32; off; off >>= 1) s += __shfl_down(s, off, 64);
    __shared__ float wsum[4];
    if ((tid & 63) == 0) wsum[tid >> 6] = s;
    __syncthreads();
    if (tid == 0) out[0] = 1.0f - (wsum[0] + wsum[1] + wsum[2] + wsum[3]) * inv_count;
}

extern "C" void kernel_launch(void* const* d_in, const int* in_sizes, int n_in,
                              void* d_out, int out_size, void* d_ws, size_t ws_size,
                              hipStream_t stream)
{
    const float* X  = (const float*)d_in[0];
    const float* Y  = (const float*)d_in[1];
    const float* DR = (const float*)d_in[2];
    float* out      = (float*)d_out;
    float* partials = (float*)d_ws;

    const int gx = (OW + CW - 1) / CW;   // 8
    const int gy = (OH + SH - 1) / SH;   // 8
    dim3 grid(gx, gy, B);                // 4096 blocks, every partial slot written
    ssim_main<<<grid, 256, 0, stream>>>(X, Y, DR, partials);

    const int n = gx * gy * B;           // 4096
    const float inv_count = 1.0f / (float)((long)B * OH * OW);
    ssim_final<<<1, 256, 0, stream>>>(partials, n, out, inv_count);
}

// Round 8
// 50.448 us; speedup vs baseline: 2.9546x; 2.9546x over previous
//
#include <hip/hip_runtime.h>

// SSIM loss, 7x7 uniform window, VALID, over (64,1,512,512) fp32.
// R8 = R7 + bugfix: waves now own DISTINCT 64-col strips
// (c0 = bx*256 + wid*64; R7 had all 4 waves on the same strip -> 4x redundant
// work and 4x S over-count). Barrier-free main loop (wave-private LDS rows),
// row prefetch, fast rcp, no launch_bounds pin.

constexpr int B  = 64;
constexpr int H  = 512, W = 512;
constexpr int OH = H - 6, OW = W - 6;     // 506
constexpr int CW = 64;                    // output cols per wave
constexpr int BW_ = 4 * CW;               // output cols per block (256)
constexpr int SH = 64;                    // output rows per block

constexpr float INV_NP    = 1.0f / 49.0f;
constexpr float COV_NORM  = 49.0f / 48.0f;

__global__ __launch_bounds__(256)
void ssim_main(const float* __restrict__ X, const float* __restrict__ Y,
               const float* __restrict__ DR, float* __restrict__ partials)
{
    const int tid  = threadIdx.x;
    const int wid  = tid >> 6;
    const int lane = tid & 63;
    const int c0   = blockIdx.x * BW_ + wid * CW;   // wave-private strip
    const int r0   = blockIdx.y * SH;
    const int b    = blockIdx.z;

    const int out_rows = min(SH, OH - r0);
    const int rows_in  = out_rows + 6;       // <= 70

    const float d  = DR[b];
    const float C1 = (0.01f * d) * (0.01f * d);
    const float C2 = (0.03f * d) * (0.03f * d);

    const size_t base = (size_t)b * H * W + (size_t)r0 * W;
    const float* xp  = X + base + c0 + lane;
    const float* yp  = Y + base + c0 + lane;
    const float* xph = X + base + c0 + CW + lane;   // halo, lanes 0..5
    const float* yph = Y + base + c0 + CW + lane;

    const bool halo_ok  = (lane < 6) && (c0 + CW + lane < W);
    const bool colvalid = (c0 + lane) < OW;

    // wave-private double-buffered row: {x,y} pairs, 70 used per slot
    __shared__ float2 rb[4][2][CW + 8];

    // vertical circular buffers (statically indexed via 7x unroll)
    float bx[7], by[7], bxx[7], byy[7], bxy[7];
    float vsx = 0.f, vsy = 0.f, vsxx = 0.f, vsyy = 0.f, vsxy = 0.f;
#pragma unroll
    for (int i = 0; i < 7; ++i) { bx[i]=by[i]=bxx[i]=byy[i]=bxy[i]=0.f; }

    float acc = 0.f;

    // prefetch registers for the next input row
    float2 pre, preh;
    pre.x  = xp[0];
    pre.y  = yp[0];
    preh.x = halo_ok ? xph[0] : 0.f;
    preh.y = halo_ok ? yph[0] : 0.f;
    xp += W; yp += W; xph += W; yph += W;

    for (int rr = 0; rr < 70; rr += 7) {
#pragma unroll
        for (int p = 0; p < 7; ++p) {
            const int r = rr + p;                  // r % 7 == p
            if (r < rows_in) {                     // block-uniform condition
                float2* buf = rb[wid][r & 1];
                buf[lane] = pre;
                if (lane < 6) buf[CW + lane] = preh;
                // no barrier: wave-private region, DS ops in order per wave

                // issue next row's global loads; latency hides under compute
                if (r + 1 < rows_in) {
                    pre.x = xp[0];
                    pre.y = yp[0];
                    if (lane < 6) {
                        preh.x = halo_ok ? xph[0] : 0.f;
                        preh.y = halo_ok ? yph[0] : 0.f;
                    }
                    xp += W; yp += W; xph += W; yph += W;
                }

                // horizontal 7-tap sums of the 5 channels
                float hx = 0.f, hy = 0.f, hxx = 0.f, hyy = 0.f, hxy = 0.f;
#pragma unroll
                for (int i = 0; i < 7; ++i) {
                    const float2 v = buf[lane + i];
                    hx += v.x; hy += v.y;
                    hxx = fmaf(v.x, v.x, hxx);
                    hyy = fmaf(v.y, v.y, hyy);
                    hxy = fmaf(v.x, v.y, hxy);
                }

                // vertical running 7-row window (slot p holds row r-7's value)
                vsx  += hx  - bx[p];  bx[p]  = hx;
                vsy  += hy  - by[p];  by[p]  = hy;
                vsxx += hxx - bxx[p]; bxx[p] = hxx;
                vsyy += hyy - byy[p]; byy[p] = hyy;
                vsxy += hxy - bxy[p]; bxy[p] = hxy;

                if (r >= 6 && colvalid) {
                    const float ux  = vsx  * INV_NP;
                    const float uy  = vsy  * INV_NP;
                    const float uxx = vsxx * INV_NP;
                    const float uyy = vsyy * INV_NP;
                    const float uxy = vsxy * INV_NP;
                    const float vx  = COV_NORM * (uxx - ux * ux);
                    const float vy  = COV_NORM * (uyy - uy * uy);
                    const float vxy = COV_NORM * (uxy - ux * uy);
                    const float A1 = 2.f * ux * uy + C1;
                    const float A2 = 2.f * vxy + C2;
                    const float B1 = ux * ux + uy * uy + C1;
                    const float B2 = vx + vy + C2;
                    const float den = B1 * B2;
                    float rcp = __builtin_amdgcn_rcpf(den);
                    rcp = rcp * (2.f - den * rcp);      // 1 Newton step
                    acc = fmaf(A1 * A2, rcp, acc);
                }
            }
        }
    }

    // block reduction: wave shfl, then cross-wave via LDS (single barrier)
    float s = acc;
#pragma unroll
    for (int off = 32; off; off >>= 1) s += __shfl_down(s, off, 64);
    __shared__ float wsum[4];
    if (lane == 0) wsum[wid] = s;
    __syncthreads();
    if (tid == 0) {
        const int bid = (blockIdx.z * gridDim.y + blockIdx.y) * gridDim.x + blockIdx.x;
        partials[bid] = wsum[0] + wsum[1] + wsum[2] + wsum[3];
    }
}

__global__ __launch_bounds__(256)
void ssim_final(const float* __restrict__ partials, int n,
                float* __restrict__ out, float inv_count)
{
    const int tid = threadIdx.x;
    float s = 0.f;
    for (int i = tid; i < n; i += 256) s += partials[i];
#pragma unroll
    for (int off = 32; off; off >>= 1) s += __shfl_down(s, off, 64);
    __shared__ float wsum[4];
    if ((tid & 63) == 0) wsum[tid >> 6] = s;
    __syncthreads();
    if (tid == 0) out[0] = 1.0f - (wsum[0] + wsum[1] + wsum[2] + wsum[3]) * inv_count;
}

extern "C" void kernel_launch(void* const* d_in, const int* in_sizes, int n_in,
                              void* d_out, int out_size, void* d_ws, size_t ws_size,
                              hipStream_t stream)
{
    const float* X  = (const float*)d_in[0];
    const float* Y  = (const float*)d_in[1];
    const float* DR = (const float*)d_in[2];
    float* out      = (float*)d_out;
    float* partials = (float*)d_ws;

    const int gx = (OW + BW_ - 1) / BW_; // 2
    const int gy = (OH + SH - 1) / SH;   // 8
    dim3 grid(gx, gy, B);                // 1024 blocks, every partial slot written
    ssim_main<<<grid, 256, 0, stream>>>(X, Y, DR, partials);

    const int n = gx * gy * B;           // 1024
    const float inv_count = 1.0f / (float)((long)B * OH * OW);
    ssim_final<<<1, 256, 0, stream>>>(partials, n, out, inv_count);
}

// Round 12
// 46.902 us; speedup vs baseline: 3.1780x; 1.0756x over previous
//
#include <hip/hip_runtime.h>

// SSIM loss, 7x7 uniform window, VALID, over (64,1,512,512) fp32.
// R9 = R8 + (1) depth-2 row prefetch (14-wide unroll; parity p&1 and circ
// slot p%7 both static), (2) 32-bit saddr offsets, 1 incr/row, clamped halo
// addr (no per-iter cndmask), (3) normalization-cancelled SSIM algebra
// (raw window sums, c1s=2401*C1, c2s=2352*C2), (4) single LDS row buffer
// (DS ops in-order per wave). Barrier-free main loop, wave-private strips.

constexpr int B  = 64;
constexpr int H  = 512, W = 512;
constexpr int OH = H - 6, OW = W - 6;     // 506
constexpr int CW = 64;                    // output cols per wave
constexpr int BW_ = 4 * CW;               // output cols per block (256)
constexpr int SH = 64;                    // output rows per block

__global__ __launch_bounds__(256)
void ssim_main(const float* __restrict__ X, const float* __restrict__ Y,
               const float* __restrict__ DR, float* __restrict__ partials)
{
    const int tid  = threadIdx.x;
    const int wid  = tid >> 6;
    const int lane = tid & 63;
    const int c0   = blockIdx.x * BW_ + wid * CW;   // wave-private strip
    const int r0   = blockIdx.y * SH;
    const int b    = blockIdx.z;

    const int out_rows = min(SH, OH - r0);
    const int rows_in  = out_rows + 6;       // 70, or 64 on last strip

    const float d  = DR[b];
    const float C1 = (0.01f * d) * (0.01f * d);
    const float C2 = (0.03f * d) * (0.03f * d);
    const float c1s = 2401.0f * C1;          // 49^2 * C1
    const float c2s = 2352.0f * C2;          // 48*49 * C2

    const float* __restrict__ Xb = X + (size_t)b * H * W;
    const float* __restrict__ Yb = Y + (size_t)b * H * W;

    // 32-bit offsets, one increment per row; halo address clamped in-bounds
    // (clamped values only ever feed invalid outputs)
    unsigned off  = (unsigned)(r0 * W + c0 + lane);
    unsigned hoff = (unsigned)(r0 * W + min(c0 + CW + lane, W - 1));

    const bool colvalid = (c0 + lane) < OW;
    const bool is_halo  = lane < 6;

    // wave-private single row buffer: {x,y} pairs, 70 used
    __shared__ float2 rb[4][CW + 8];
    float2* const buf = rb[wid];

    // vertical circular buffers (statically indexed via unroll)
    float bx[7], by[7], bxx[7], byy[7], bxy[7];
    float vsx = 0.f, vsy = 0.f, vsxx = 0.f, vsyy = 0.f, vsxy = 0.f;
#pragma unroll
    for (int i = 0; i < 7; ++i) { bx[i]=by[i]=bxx[i]=byy[i]=bxy[i]=0.f; }

    float acc = 0.f;

    // depth-2 prefetch: pre0/preh0 = even rows, pre1/preh1 = odd rows
    float2 pre0, pre1;
    float2 preh0 = make_float2(0.f, 0.f), preh1 = make_float2(0.f, 0.f);
    pre0.x = Xb[off]; pre0.y = Yb[off];
    if (is_halo) { preh0.x = Xb[hoff]; preh0.y = Yb[hoff]; }
    off += W; hoff += W;
    pre1.x = Xb[off]; pre1.y = Yb[off];
    if (is_halo) { preh1.x = Xb[hoff]; preh1.y = Yb[hoff]; }
    off += W; hoff += W;

    for (int rr = 0; rr < 70; rr += 14) {
#pragma unroll
        for (int p = 0; p < 14; ++p) {
            const int r = rr + p;              // r%7 == p%7, r&1 == p&1
            if (r < rows_in) {                 // block-uniform
                float2& pr = (p & 1) ? pre1 : pre0;
                float2& ph = (p & 1) ? preh1 : preh0;
                buf[lane] = pr;
                if (is_halo) buf[CW + lane] = ph;
                // no barrier: wave-private region, DS ops in order per wave

                // issue row r+2's loads now; 2 iterations of latency cover
                if (r + 2 < rows_in) {
                    pr.x = Xb[off]; pr.y = Yb[off];
                    if (is_halo) { ph.x = Xb[hoff]; ph.y = Yb[hoff]; }
                    off += W; hoff += W;
                }

                // horizontal 7-tap sums of the 5 channels
                float hx = 0.f, hy = 0.f, hxx = 0.f, hyy = 0.f, hxy = 0.f;
#pragma unroll
                for (int i = 0; i < 7; ++i) {
                    const float2 v = buf[lane + i];
                    hx += v.x; hy += v.y;
                    hxx = fmaf(v.x, v.x, hxx);
                    hyy = fmaf(v.y, v.y, hyy);
                    hxy = fmaf(v.x, v.y, hxy);
                }

                // vertical running 7-row window (slot p%7 holds row r-7)
                constexpr int s7[14] = {0,1,2,3,4,5,6,0,1,2,3,4,5,6};
                const int sp = s7[p];
                vsx  += hx  - bx[sp];  bx[sp]  = hx;
                vsy  += hy  - by[sp];  by[sp]  = hy;
                vsxx += hxx - bxx[sp]; bxx[sp] = hxx;
                vsyy += hyy - byy[sp]; byy[sp] = hyy;
                vsxy += hxy - bxy[sp]; bxy[sp] = hxy;

                if (r >= 6 && colvalid) {
                    // normalization-cancelled SSIM on raw sums:
                    // S = (2 sx sy + c1s)(2(49 sxy - sx sy) + c2s)
                    //   / (sx^2+sy^2+c1s)(49(sxx+syy) - sx^2 - sy^2 + c2s)
                    const float p1 = vsx * vsy;
                    const float t1 = fmaf(2.f, p1, c1s);
                    const float q  = fmaf(49.f, vsxy, -p1);
                    const float t2 = fmaf(2.f, q, c2s);
                    const float n1 = vsx * vsx;
                    const float n2 = fmaf(vsy, vsy, n1);
                    const float b1 = n2 + c1s;
                    const float s3 = vsxx + vsyy;
                    const float b2 = fmaf(49.f, s3, c2s) - n2;
                    const float num = t1 * t2;
                    const float den = b1 * b2;
                    float rcp = __builtin_amdgcn_rcpf(den);
                    rcp = rcp * (2.f - den * rcp);      // 1 Newton step
                    acc = fmaf(num, rcp, acc);
                }
            }
        }
    }

    // block reduction: wave shfl, then cross-wave via LDS (single barrier)
    float s = acc;
#pragma unroll
    for (int offr = 32; offr; offr >>= 1) s += __shfl_down(s, offr, 64);
    __shared__ float wsum[4];
    if (lane == 0) wsum[wid] = s;
    __syncthreads();
    if (tid == 0) {
        const int bid = (blockIdx.z * gridDim.y + blockIdx.y) * gridDim.x + blockIdx.x;
        partials[bid] = wsum[0] + wsum[1] + wsum[2] + wsum[3];
    }
}

__global__ __launch_bounds__(256)
void ssim_final(const float* __restrict__ partials, int n,
                float* __restrict__ out, float inv_count)
{
    const int tid = threadIdx.x;
    float s = 0.f;
    for (int i = tid; i < n; i += 256) s += partials[i];
#pragma unroll
    for (int off = 32; off; off >>= 1) s += __shfl_down(s, off, 64);
    __shared__ float wsum[4];
    if ((tid & 63) == 0) wsum[tid >> 6] = s;
    __syncthreads();
    if (tid == 0) out[0] = 1.0f - (wsum[0] + wsum[1] + wsum[2] + wsum[3]) * inv_count;
}

extern "C" void kernel_launch(void* const* d_in, const int* in_sizes, int n_in,
                              void* d_out, int out_size, void* d_ws, size_t ws_size,
                              hipStream_t stream)
{
    const float* X  = (const float*)d_in[0];
    const float* Y  = (const float*)d_in[1];
    const float* DR = (const float*)d_in[2];
    float* out      = (float*)d_out;
    float* partials = (float*)d_ws;

    const int gx = (OW + BW_ - 1) / BW_; // 2
    const int gy = (OH + SH - 1) / SH;   // 8
    dim3 grid(gx, gy, B);                // 1024 blocks, every partial slot written
    ssim_main<<<grid, 256, 0, stream>>>(X, Y, DR, partials);

    const int n = gx * gy * B;           // 1024
    const float inv_count = 1.0f / (float)((long)B * OH * OW);
    ssim_final<<<1, 256, 0, stream>>>(partials, n, out, inv_count);
}